// Round 11
// baseline (25.409 us; speedup 1.0000x reference)
//
#include <hip/hip_runtime.h>

#define BATCH 4096
#define CLEN  8192
#define COEF  0.1f
#define NT    256
#define RPB   2                      // rows per block
#define NBLK  (BATCH / RPB)          // 2048 blocks, 8/CU -> 32 waves/CU

// Native clang vector type: __builtin_nontemporal_load requires a pointer to
// scalar/vector-of-scalar, not HIP_vector_type (a struct).
typedef float f32x4 __attribute__((ext_vector_type(4)));

// Phase 1: block b computes ws[b] = sum over its 2 rows of
//   inv_norm(t_row) * sum_i |i - t_row| * exp(x[row,i])
// Round-10 + explicit depth-1 software pipeline: prefetch k+1's two float4s
// before computing k, so >=4 loads are structurally in flight per thread.
// __launch_bounds__(NT,8) pins the allocator under the 64-VGPR cliff
// (8 blocks/CU = 32 waves/CU).
__global__ __launch_bounds__(NT, 8) void dfal_rows_kernel(
    const float* __restrict__ in,
    const int*   __restrict__ target,
    float*       __restrict__ ws)
{
    const int b   = blockIdx.x;
    const int tid = threadIdx.x;

    const int row0 = b * RPB;
    const int row1 = row0 + 1;

    const long long t0 = (long long)target[row0];
    const long long t1 = (long long)target[row1];

    // Exact sum of squared distances sum_{i=0}^{C-1} (i-t)^2, closed form.
    const long long m0  = (long long)(CLEN - 1) - t0;
    const long long ss0 = t0 * (t0 + 1) * (2 * t0 + 1) / 6
                        + m0 * (m0 + 1) * (2 * m0 + 1) / 6;
    const float inv_norm0 = (t0 == 0) ? 0.0f : (float)(1.0 / sqrt((double)ss0));
    const long long m1  = (long long)(CLEN - 1) - t1;
    const long long ss1 = t1 * (t1 + 1) * (2 * t1 + 1) / 6
                        + m1 * (m1 + 1) * (2 * m1 + 1) / 6;
    const float inv_norm1 = (t1 == 0) ? 0.0f : (float)(1.0 / sqrt((double)ss1));

    const float tf0 = (float)t0;
    const float tf1 = (float)t1;
    const f32x4* __restrict__ inA = (const f32x4*)(in + (size_t)row0 * CLEN);
    const f32x4* __restrict__ inB = (const f32x4*)(in + (size_t)row1 * CLEN);

    float p0 = 0.0f, p1 = 0.0f;

    f32x4 xa = __builtin_nontemporal_load(&inA[tid]);
    f32x4 xb = __builtin_nontemporal_load(&inB[tid]);
#pragma unroll
    for (int k = 0; k < 8; ++k) {           // 2 x 8 float4/thread, coalesced
        f32x4 na, nb;
        if (k < 7) {                        // prefetch k+1 before computing k
            const int jn = tid + (k + 1) * NT;
            na = __builtin_nontemporal_load(&inA[jn]);
            nb = __builtin_nontemporal_load(&inB[jn]);
        }
        const float i0 = (float)(4 * (tid + k * NT));
        p0 = fmaf(fabsf(i0        - tf0), __expf(xa.x), p0);
        p0 = fmaf(fabsf(i0 + 1.0f - tf0), __expf(xa.y), p0);
        p0 = fmaf(fabsf(i0 + 2.0f - tf0), __expf(xa.z), p0);
        p0 = fmaf(fabsf(i0 + 3.0f - tf0), __expf(xa.w), p0);
        p1 = fmaf(fabsf(i0        - tf1), __expf(xb.x), p1);
        p1 = fmaf(fabsf(i0 + 1.0f - tf1), __expf(xb.y), p1);
        p1 = fmaf(fabsf(i0 + 2.0f - tf1), __expf(xb.z), p1);
        p1 = fmaf(fabsf(i0 + 3.0f - tf1), __expf(xb.w), p1);
        xa = na; xb = nb;
    }
    // Per-row scale, fixed order (same arithmetic as rounds 9-10).
    float acc = fmaf(inv_norm1, p1, inv_norm0 * p0);

    // Wave (64-lane) reduction, then cross-wave via LDS.
#pragma unroll
    for (int off = 32; off; off >>= 1) acc += __shfl_down(acc, off, 64);

    __shared__ float wsum[NT / 64];
    if ((tid & 63) == 0) wsum[tid >> 6] = acc;
    __syncthreads();
    if (tid == 0) ws[b] = wsum[0] + wsum[1] + wsum[2] + wsum[3];
}

// Phase 2: one wave, no LDS, no syncthreads. 2048 floats (8 KB) -> scalar.
__global__ __launch_bounds__(64) void dfal_final_kernel(
    const float* __restrict__ ws,
    float*       __restrict__ out)
{
    const int tid = threadIdx.x;
    float s = 0.0f;
#pragma unroll
    for (int i = 0; i < NBLK / 64; ++i)     // 32 per lane, fixed order
        s += ws[tid + i * 64];
#pragma unroll
    for (int off = 32; off; off >>= 1) s += __shfl_down(s, off, 64);
    if (tid == 0) out[0] = s * COEF;
}

extern "C" void kernel_launch(void* const* d_in, const int* in_sizes, int n_in,
                              void* d_out, int out_size, void* d_ws, size_t ws_size,
                              hipStream_t stream) {
    const float* input  = (const float*)d_in[0];
    const int*   target = (const int*)d_in[1];
    float* out = (float*)d_out;
    float* ws  = (float*)d_ws;   // NBLK floats, fully rewritten every call

    dfal_rows_kernel<<<NBLK, NT, 0, stream>>>(input, target, ws);
    dfal_final_kernel<<<1, 64, 0, stream>>>(ws, out);
}